// Round 11
// baseline (227.074 us; speedup 1.0000x reference)
//
#include <hip/hip_runtime.h>
#include <hip/hip_bf16.h>

#define TT 8192
#define DD 64
#define BB 2
#define NROWS (BB * TT)  // 16384
#define L2E 1.4426950408889634f

typedef __attribute__((ext_vector_type(8))) short bf16x8;
typedef __attribute__((ext_vector_type(4))) float f32x4;
typedef _Float16 f16x4 __attribute__((ext_vector_type(4)));
typedef __fp16 fp16x2 __attribute__((ext_vector_type(2)));

#define MFMAQK __builtin_amdgcn_mfma_f32_16x16x32_bf16
#define MFMAPV __builtin_amdgcn_mfma_f32_16x16x16f16

typedef __attribute__((address_space(1))) const unsigned int gu32;
typedef __attribute__((address_space(3))) unsigned int lu32;

__device__ inline void gld_lds16(const unsigned short* g, unsigned short* l) {
  __builtin_amdgcn_global_load_lds((gu32*)g, (lu32*)l, 16, 0, 0);
}

// ws: xb 2MB | xth 2MB | m2[16384] | mm2[16384] | l[16384] | part up to 3x4MB

__device__ inline unsigned short f2bf(float f) {
  unsigned int u = __float_as_uint(f);
  u += 0x7FFF + ((u >> 16) & 1);
  return (unsigned short)(u >> 16);
}
__device__ inline float bf2f(unsigned short h) {
  return __uint_as_float(((unsigned int)h) << 16);
}
__device__ inline f16x4 pk4f16(float a, float b, float c, float d) {
  union { fp16x2 h2[2]; f16x4 h4; } u;
  u.h2[0] = __builtin_amdgcn_cvt_pkrtz(a, b);
  u.h2[1] = __builtin_amdgcn_cvt_pkrtz(c, d);
  return u.h4;
}

// ---------- ka: bf16 xb + f16 transposed xth + m2 = |x|^2 * log2e ----------
__global__ __launch_bounds__(256) void ka_init(const float* __restrict__ x,
                                               unsigned short* __restrict__ xb,
                                               unsigned short* __restrict__ xth,
                                               float* __restrict__ m2) {
  __shared__ __align__(16) unsigned short tile[64 * 72];
  int t = threadIdx.x;
  int r0 = blockIdx.x * 64;
  int rloc = t >> 2, part = t & 3;
  int r = r0 + rloc;
  const float4* px = (const float4*)(x + (size_t)r * DD + part * 16);
  unsigned short h[16], hf[16];
  float msum = 0.f;
#pragma unroll
  for (int g = 0; g < 4; ++g) {
    float4 v = px[g];
    float vv[4] = {v.x, v.y, v.z, v.w};
#pragma unroll
    for (int e = 0; e < 4; ++e) {
      unsigned short hb = f2bf(vv[e]);
      h[g * 4 + e] = hb;
      float f = bf2f(hb);
      msum += f * f;
      _Float16 hh = (_Float16)vv[e];
      hf[g * 4 + e] = *(unsigned short*)&hh;
    }
  }
  uint4* xbr = (uint4*)(xb + (size_t)r * DD + part * 16);
#pragma unroll
  for (int g = 0; g < 2; ++g) {
    uint4 v;
    v.x = (unsigned int)h[g * 8 + 0] | ((unsigned int)h[g * 8 + 1] << 16);
    v.y = (unsigned int)h[g * 8 + 2] | ((unsigned int)h[g * 8 + 3] << 16);
    v.z = (unsigned int)h[g * 8 + 4] | ((unsigned int)h[g * 8 + 5] << 16);
    v.w = (unsigned int)h[g * 8 + 6] | ((unsigned int)h[g * 8 + 7] << 16);
    xbr[g] = v;
  }
#pragma unroll
  for (int k = 0; k < 16; ++k) tile[(part * 16 + k) * 72 + rloc] = hf[k];
  msum += __shfl_xor(msum, 1, 64);
  msum += __shfl_xor(msum, 2, 64);
  if (part == 0) m2[r] = msum * L2E;
  __syncthreads();
  int d = t >> 2, seg = t & 3;
  int b = r0 >> 13;
  int tcol = (r0 & (TT - 1)) + seg * 16;
  uint4 v0 = *(uint4*)(tile + d * 72 + seg * 16);
  uint4 v1 = *(uint4*)(tile + d * 72 + seg * 16 + 8);
  uint4* dst = (uint4*)(xth + ((size_t)b * DD + d) * TT + tcol);
  dst[0] = v0;
  dst[1] = v1;
}

// ---------- kb: l_j += sum_k 2^(s*log2e - m2_j) over k-split ----------
__global__ __launch_bounds__(256) void kb_l(const unsigned short* __restrict__ xq,
                                            const float* __restrict__ m2,
                                            float* __restrict__ l) {
  __shared__ __align__(16) unsigned short kslab[4][2][1024];  // 16 KB
  __shared__ float lpart[4][32];
  int w = threadIdx.x >> 6, lane = threadIdx.x & 63;
  int c = lane & 15, q = lane >> 4;
  int b = blockIdx.z;
  int j0g = b * TT + blockIdx.x * 32;
  bf16x8 a0[2], a1[2];
  f32x4 mv[2];
#pragma unroll
  for (int u = 0; u < 2; ++u) {
    const unsigned short* pr = xq + (size_t)(j0g + u * 16 + c) * DD + q * 8;
    a0[u] = *(const bf16x8*)pr;
    a1[u] = *(const bf16x8*)(pr + 32);
    mv[u] = *(const f32x4*)(m2 + j0g + u * 16 + 4 * q);
  }
  const unsigned short* xqb = xq + (size_t)(b * TT) * DD;
  int k0 = blockIdx.y * 2048 + w * 512;
  int srow = lane >> 3;
  int sch = (lane & 7) ^ srow;
  unsigned short* sb = &kslab[w][0][0];
  auto stage = [&](int buf, int kbase) {
#pragma unroll
    for (int t = 0; t < 2; ++t)
      gld_lds16(xqb + (size_t)(kbase + t * 8 + srow) * DD + sch * 8,
                sb + buf * 1024 + t * 512);
  };
  stage(0, k0);
  float ls[2][4] = {{0.f, 0.f, 0.f, 0.f}, {0.f, 0.f, 0.f, 0.f}};
  int o1 = (q ^ (c & 7)) * 8, o2 = ((q | 4) ^ (c & 7)) * 8;
  for (int it = 0; it < 32; ++it) {
    if (it < 31) {
      stage((it & 1) ^ 1, k0 + (it + 1) * 16);
      __builtin_amdgcn_s_waitcnt(0xF72);
    } else {
      __builtin_amdgcn_s_waitcnt(0xF70);
    }
    __builtin_amdgcn_sched_barrier(0);
    const unsigned short* kp = sb + (it & 1) * 1024;
    bf16x8 b00 = *(const bf16x8*)(kp + c * 64 + o1);
    bf16x8 b01 = *(const bf16x8*)(kp + c * 64 + o2);
#pragma unroll
    for (int u = 0; u < 2; ++u) {
      f32x4 z = {0.f, 0.f, 0.f, 0.f};
      f32x4 acc = MFMAQK(a0[u], b00, z, 0, 0, 0);
      acc = MFMAQK(a1[u], b01, acc, 0, 0, 0);
#pragma unroll
      for (int e = 0; e < 4; ++e)
        ls[u][e] += exp2f(fmaf(acc[e], L2E, -mv[u][e]));
    }
  }
#pragma unroll
  for (int u = 0; u < 2; ++u)
#pragma unroll
    for (int e = 0; e < 4; ++e) {
      float v = ls[u][e];
      v += __shfl_xor(v, 1, 64);
      v += __shfl_xor(v, 2, 64);
      v += __shfl_xor(v, 4, 64);
      v += __shfl_xor(v, 8, 64);
      if (c == 0) lpart[w][u * 16 + 4 * q + e] = v;
    }
  __syncthreads();
  int t = threadIdx.x;
  if (t < 32) {
    float s = lpart[0][t] + lpart[1][t] + lpart[2][t] + lpart[3][t];
    atomicAdd(&l[j0g + t], s);
  }
}

__global__ __launch_bounds__(256) void kb2(const float* __restrict__ m2,
                                           const float* __restrict__ l,
                                           float* __restrict__ mm2) {
  int r = blockIdx.x * 256 + threadIdx.x;
  mm2[r] = m2[r] + __log2f(l[r]);
}

// ---------- kc: out[b][d][i] = sum_j 2^(s*log2e - mm2_j) * x_j[d] ----------
// grid (256 i-tiles, S j-splits, 2 batch); block = 32 i; wave w sweeps TT/S/4 j
// in 16-j steps; A+V private DMA slabs, vmcnt(5); f16 PV (no transform).
// V swizzle includes (d>>2)&1 -> ds_read_b64 2-way only (free).
template <int S>
__global__ __launch_bounds__(256) void kc_out(const unsigned short* __restrict__ xq,
                                              const unsigned short* __restrict__ xth,
                                              const float* __restrict__ mm2,
                                              float* __restrict__ out,
                                              float* __restrict__ part) {
  __shared__ __align__(16) unsigned short smem[16384];  // A 8KB | V 8KB; epi 32KB
  int w = threadIdx.x >> 6, lane = threadIdx.x & 63;
  int c = lane & 15, q = lane >> 4;
  int b = blockIdx.z;
  int i0 = blockIdx.x * 32;
  bf16x8 bq0[2], bq1[2];
#pragma unroll
  for (int u = 0; u < 2; ++u) {
    const unsigned short* pr = xq + (size_t)(b * TT + i0 + u * 16 + c) * DD + q * 8;
    bq0[u] = *(const bf16x8*)pr;
    bq1[u] = *(const bf16x8*)(pr + 32);
  }
  f32x4 o[2][4];
#pragma unroll
  for (int u = 0; u < 2; ++u)
#pragma unroll
    for (int nt = 0; nt < 4; ++nt) o[u][nt] = (f32x4){0.f, 0.f, 0.f, 0.f};

  const unsigned short* xqb = xq + (size_t)(b * TT) * DD;
  const unsigned short* xtb = xth + (size_t)b * DD * TT;
  const float* mmb = mm2 + b * TT;
  const int JW = TT / S / 4;        // j per wave
  const int NIT = JW / 16;
  int jq0 = blockIdx.y * (TT / S) + w * JW;
  unsigned short* asb = smem + w * 2048;
  unsigned short* vsb = smem + 8192 + w * 2048;

  int srow = lane >> 3;
  int sch = (lane & 7) ^ srow;
  int vd = lane >> 1;
  int vg = (lane & 1) ^ (vd & 1) ^ ((vd >> 2) & 1);
  auto stage = [&](int buf, int j) {
#pragma unroll
    for (int t = 0; t < 2; ++t)
      gld_lds16(xqb + (size_t)(j + t * 8 + srow) * DD + sch * 8,
                asb + buf * 1024 + t * 512);
#pragma unroll
    for (int t = 0; t < 2; ++t)
      gld_lds16(xtb + (size_t)(t * 32 + vd) * TT + j + 8 * vg,
                vsb + buf * 1024 + t * 512);
  };
  f32x4 mv[2];
  stage(0, jq0);
  mv[0] = *(const f32x4*)(mmb + jq0 + 4 * q);

  int o1 = (q ^ (c & 7)) * 8, o2 = ((q | 4) ^ (c & 7)) * 8;
  int voff = c * 16 + 8 * ((q >> 1) ^ (c & 1) ^ ((c >> 2) & 1)) + 4 * (q & 1);

  for (int it = 0; it < NIT; ++it) {
    int cur = it & 1;
    int jt = jq0 + it * 16;
    if (it < NIT - 1) {
      stage(cur ^ 1, jt + 16);
      mv[cur ^ 1] = *(const f32x4*)(mmb + jt + 16 + 4 * q);
      __builtin_amdgcn_s_waitcnt(0xF75);
    } else {
      __builtin_amdgcn_s_waitcnt(0xF70);
    }
    __builtin_amdgcn_sched_barrier(0);
    const unsigned short* ap = asb + cur * 1024;
    const unsigned short* vp = vsb + cur * 1024;
    bf16x8 a0f = *(const bf16x8*)(ap + c * 64 + o1);
    bf16x8 a1f = *(const bf16x8*)(ap + c * 64 + o2);
    f16x4 bv[4];
#pragma unroll
    for (int nt = 0; nt < 4; ++nt) bv[nt] = *(const f16x4*)(vp + nt * 256 + voff);
#pragma unroll
    for (int u = 0; u < 2; ++u) {
      f32x4 z = {0.f, 0.f, 0.f, 0.f};
      f32x4 s = MFMAQK(a0f, bq0[u], z, 0, 0, 0);
      s = MFMAQK(a1f, bq1[u], s, 0, 0, 0);
      f16x4 p = pk4f16(exp2f(fmaf(s[0], L2E, -mv[cur][0])),
                       exp2f(fmaf(s[1], L2E, -mv[cur][1])),
                       exp2f(fmaf(s[2], L2E, -mv[cur][2])),
                       exp2f(fmaf(s[3], L2E, -mv[cur][3])));
#pragma unroll
      for (int nt = 0; nt < 4; ++nt) o[u][nt] = MFMAPV(p, bv[nt], o[u][nt], 0, 0, 0);
    }
  }
  __syncthreads();
  float* ow = (float*)smem + w * 2048;
#pragma unroll
  for (int u = 0; u < 2; ++u)
#pragma unroll
    for (int nt = 0; nt < 4; ++nt)
      *(f32x4*)(ow + (nt * 16 + c) * 32 + u * 16 + 4 * q) = o[u][nt];
  __syncthreads();
  int t = threadIdx.x, d = t >> 2, i8 = (t & 3) * 8;
  const float* sbase = (const float*)smem;
  f32x4 sA = {0.f, 0.f, 0.f, 0.f}, sB = {0.f, 0.f, 0.f, 0.f};
#pragma unroll
  for (int ww = 0; ww < 4; ++ww) {
    const float* p = sbase + ww * 2048 + d * 32 + i8;
    sA += *(const f32x4*)p;
    sB += *(const f32x4*)(p + 4);
  }
  float* dst = (blockIdx.y == 0) ? out : (part + (size_t)(blockIdx.y - 1) * (BB * DD * TT));
  float* ob = dst + ((size_t)(b * DD + d)) * TT + i0 + i8;
  *(f32x4*)ob = sA;
  *(f32x4*)(ob + 4) = sB;
}

// ---------- kd: out += sum of ns partials ----------
__global__ __launch_bounds__(256) void kd_add(float* __restrict__ out,
                                              const float* __restrict__ part, int ns) {
  int t = blockIdx.x * 256 + threadIdx.x;
  f32x4* o4 = (f32x4*)out;
  const f32x4* p4 = (const f32x4*)part;
  f32x4 s = o4[t];
  for (int p = 0; p < ns; ++p) s += p4[(size_t)p * (BB * DD * TT / 4) + t];
  o4[t] = s;
}

extern "C" void kernel_launch(void* const* d_in, const int* in_sizes, int n_in,
                              void* d_out, int out_size, void* d_ws, size_t ws_size,
                              hipStream_t stream) {
  const float* x = (const float*)d_in[0];
  float* out = (float*)d_out;
  unsigned short* xb = (unsigned short*)d_ws;
  unsigned short* xth = xb + (size_t)NROWS * DD;
  float* m2 = (float*)(xth + (size_t)NROWS * DD);
  float* mm2 = m2 + NROWS;
  float* l = mm2 + NROWS;
  float* part = l + NROWS;
  size_t base = (size_t)((char*)part - (char*)d_ws);
  bool big = ws_size >= base + 3ull * BB * DD * TT * sizeof(float);

  hipMemsetAsync(l, 0, NROWS * sizeof(float), stream);
  ka_init<<<NROWS / 64, 256, 0, stream>>>(x, xb, xth, m2);
  kb_l<<<dim3(TT / 32, 4, BB), 256, 0, stream>>>(xb, m2, l);
  kb2<<<NROWS / 256, 256, 0, stream>>>(m2, l, mm2);
  if (big) {
    kc_out<4><<<dim3(TT / 32, 4, BB), 256, 0, stream>>>(xb, xth, mm2, out, part);
    kd_add<<<(BB * DD * TT / 4) / 256, 256, 0, stream>>>(out, part, 3);
  } else {
    kc_out<2><<<dim3(TT / 32, 2, BB), 256, 0, stream>>>(xb, xth, mm2, out, part);
    kd_add<<<(BB * DD * TT / 4) / 256, 256, 0, stream>>>(out, part, 1);
  }
}